// Round 2
// 490.204 us; speedup vs baseline: 1.1165x; 1.1165x over previous
//
#include <hip/hip_runtime.h>
#include <hip/hip_bf16.h>
#include <stdint.h>

// Problem: out[b,s,o] = alpha * sum_k x[b,s,k] * t[o,k],  t in {-1,0,+1}
// M = 4*2048 = 8192, K = 4096, N = 4096.
#define M_DIM 8192
#define K_DIM 4096
#define N_DIM 4096

typedef __attribute__((ext_vector_type(8))) short short8;
typedef __attribute__((ext_vector_type(4))) float f32x4;

// ---------------------------------------------------------------------------
// async global->LDS, 16B per lane (global_load_lds_dwordx4)
// ---------------------------------------------------------------------------
__device__ __forceinline__ void lds_load16(const ushort* g, ushort* l) {
    __builtin_amdgcn_global_load_lds(
        (const __attribute__((address_space(1))) uint32_t*)g,
        (__attribute__((address_space(3))) uint32_t*)l, 16, 0, 0);
}

__device__ __forceinline__ ushort f2bf_rne(float f) {
    uint32_t u = __float_as_uint(f);
    uint32_t r = (u + 0x7FFFu + ((u >> 16) & 1u)) >> 16;
    return (ushort)r;
}

// ---------------------------------------------------------------------------
// Pass 1a: per-block partial sums of |w|, fp64 accumulate (deterministic)
// ---------------------------------------------------------------------------
__global__ void k_abs_partial(const float* __restrict__ w, double* __restrict__ partial) {
    const float4* w4 = (const float4*)w;
    const int n4 = (K_DIM * N_DIM) / 4;  // 4194304
    double s = 0.0;
    for (int i = blockIdx.x * blockDim.x + threadIdx.x; i < n4; i += gridDim.x * blockDim.x) {
        float4 v = w4[i];
        s += (double)fabsf(v.x) + (double)fabsf(v.y) + (double)fabsf(v.z) + (double)fabsf(v.w);
    }
    #pragma unroll
    for (int off = 32; off > 0; off >>= 1) s += __shfl_down(s, off, 64);
    __shared__ double sm[4];
    int lane = threadIdx.x & 63, wv = threadIdx.x >> 6;
    if (lane == 0) sm[wv] = s;
    __syncthreads();
    if (threadIdx.x == 0) partial[blockIdx.x] = sm[0] + sm[1] + sm[2] + sm[3];
}

// Pass 1b: finalize alpha = mean(|w|)
__global__ void k_alpha(const double* __restrict__ partial, float* __restrict__ alpha_out) {
    double s = 0.0;
    for (int i = threadIdx.x; i < 1024; i += 256) s += partial[i];
    #pragma unroll
    for (int off = 32; off > 0; off >>= 1) s += __shfl_down(s, off, 64);
    __shared__ double sm[4];
    int lane = threadIdx.x & 63, wv = threadIdx.x >> 6;
    if (lane == 0) sm[wv] = s;
    __syncthreads();
    if (threadIdx.x == 0) {
        double total = sm[0] + sm[1] + sm[2] + sm[3];
        alpha_out[0] = (float)(total * (1.0 / 16777216.0));
    }
}

// ---------------------------------------------------------------------------
// Pass 2: quantize w -> ternary {-1,0,+1} as bf16 (N x K row-major)
// ---------------------------------------------------------------------------
__global__ void k_quant(const float* __restrict__ w, const float* __restrict__ alpha_p,
                        ushort* __restrict__ qw) {
    const float thr = 0.5f * alpha_p[0];
    int i = blockIdx.x * blockDim.x + threadIdx.x;  // one float4 per thread
    float4 v = ((const float4*)w)[i];
    ushort4 q;
    q.x = v.x > thr ? 0x3F80 : (v.x < -thr ? 0xBF80 : 0);
    q.y = v.y > thr ? 0x3F80 : (v.y < -thr ? 0xBF80 : 0);
    q.z = v.z > thr ? 0x3F80 : (v.z < -thr ? 0xBF80 : 0);
    q.w = v.w > thr ? 0x3F80 : (v.w < -thr ? 0xBF80 : 0);
    ((ushort4*)qw)[i] = q;
}

// Pass 3: cast x fp32 -> bf16 (RNE)
__global__ void k_cast(const float* __restrict__ x, ushort* __restrict__ xb) {
    int i = blockIdx.x * blockDim.x + threadIdx.x;  // one float4 per thread
    float4 v = ((const float4*)x)[i];
    ushort4 o;
    o.x = f2bf_rne(v.x);
    o.y = f2bf_rne(v.y);
    o.z = f2bf_rne(v.z);
    o.w = f2bf_rne(v.w);
    ((ushort4*)xb)[i] = o;
}

// ---------------------------------------------------------------------------
// Pass 4: 256x256 8-phase bf16 MFMA GEMM (m201-style template, plain HIP).
//   BM=BN=256, BK=64, 512 threads = 8 waves (2M x 4N), per-wave C = 128x64.
//   LDS 128 KiB: [buf2][A|B][half2][128 rows x 64 ushorts],
//   T2 XOR swizzle: k-chunk stored at slot = chunk ^ (row&7), applied on BOTH
//   the pre-swizzled gload_lds global source and the ds_read address (rule 21).
//   Read conflict model: slot = q ^ (r&7) -> each 16-lane quarter-wave spreads
//   over all 8 16B-columns, 2 lanes/bank-group = free (m136).
//   Per K-tile: 4 phases, quadrant order (0,0),(0,1),(1,1),(1,0);
//   staging per tile t: P1:(t+1)Ah0  P2:(t+1)Ah1  P3:(t+2)Bh0  P4:(t+2)Bh1
//   (each staged region's last reader drained >=1 barrier earlier);
//   counted vmcnt(4) at phase 4 only — loads stay in flight across barriers.
// ---------------------------------------------------------------------------
#define NT (K_DIM / 64)  // 64 K-tiles

#define MFMA16(a, b, c) __builtin_amdgcn_mfma_f32_16x16x32_bf16((a), (b), (c), 0, 0, 0)

__global__ __launch_bounds__(512, 2) void k_gemm(const ushort* __restrict__ A,  // M x K bf16
                                                 const ushort* __restrict__ B,  // N x K bf16
                                                 const float* __restrict__ alpha_p,
                                                 float* __restrict__ C) {
    // 128 KiB LDS. Layout (ushort offsets): buf*32768 + isB*16384 + half*8192.
    __shared__ __align__(16) ushort lds[65536];

    const int tid = threadIdx.x;
    const int lane = tid & 63;
    const int w = tid >> 6;       // 0..7
    const int wr = w >> 2;        // 0..1  M wave-group
    const int wc = w & 3;         // 0..3  N wave-group
    const int r = lane & 15, q = lane >> 4;

    // T1: XCD-aware bijective swizzle (512 blocks, 512 % 8 == 0)
    const int wg = blockIdx.x;
    const int swz = (wg & 7) * 64 + (wg >> 3);
    const int bm = swz >> 4;      // 0..31 (M tiles)
    const int bn = swz & 15;      // 0..15 (N tiles)

    // materialize alpha before staging so the vmcnt stream stays clean
    float alpha = alpha_p[0];
    asm volatile("" :: "v"(alpha));

    const ushort* Abase = A + (size_t)bm * 256 * K_DIM;
    const ushort* Bbase = B + (size_t)bn * 256 * K_DIM;

    // staging constants: thread stages granule g = tid of a 64-row half-tile
    // (row = tid>>3, slot = tid&7); stored logical chunk = slot ^ (row&7),
    // so the SOURCE k-chunk is pre-swizzled while LDS dest stays lane-linear.
    const int srow = tid >> 3;                // 0..63
    const int sch = (tid & 7) ^ (srow & 7);   // pre-swizzled source k-chunk

    // read constants: frag (row = f*16+r, logical chunk = s*4+q) lives at
    // slot (s*4+q) ^ (r&7)   [row&7 == r&7 since 16 | row-base]
    const int ch0 = q ^ (r & 7);
    const int o0 = r * 64 + ch0 * 8;          // s=0 ushort offset within 16-row frag
    const int o1 = r * 64 + (ch0 ^ 4) * 8;    // s=1

    f32x4 acc[8][4] = {};   // [m-frag 0..7][n-frag 0..3]

    auto SA = [&](int h, int bb, int tt) {    // stage A half h of tile tt into buf bb
        const ushort* g = Abase + (size_t)(h * 128 + srow) * K_DIM + tt * 64 + sch * 8;
        ushort* l = lds + bb * 32768 + h * 8192 + tid * 8;
        lds_load16(g, l);
        lds_load16(g + (size_t)64 * K_DIM, l + 4096);
    };
    auto SB = [&](int h, int bb, int tt) {
        const ushort* g = Bbase + (size_t)(h * 128 + srow) * K_DIM + tt * 64 + sch * 8;
        ushort* l = lds + bb * 32768 + 16384 + h * 8192 + tid * 8;
        lds_load16(g, l);
        lds_load16(g + (size_t)64 * K_DIM, l + 4096);
    };

    // ---- prologue: tile0 {A,B} complete + tile1 {B} (12 loads); leave 4 in flight
    SA(0, 0, 0); SA(1, 0, 0); SB(0, 0, 0); SB(1, 0, 0);
    SB(0, 1, 1); SB(1, 1, 1);
    asm volatile("s_waitcnt vmcnt(4)" ::: "memory");
    __builtin_amdgcn_s_barrier();

    for (int t = 0; t < NT; ++t) {
        const int b = t & 1;
        const ushort* aL = lds + b * 32768 + wr * 8192;
        const ushort* bL = lds + b * 32768 + 16384 + (wc >> 1) * 8192 + (wc & 1) * 4096;
        short8 am[4][2], b01[2][2], b23[2][2];

        // ---------------- P1: read A0(m0-3)+B01 (12 ds_read); stage (t+1)Ah0; Q(0,0)
        #pragma unroll
        for (int i = 0; i < 4; ++i) {
            am[i][0] = *(const short8*)(aL + i * 1024 + o0);
            am[i][1] = *(const short8*)(aL + i * 1024 + o1);
        }
        #pragma unroll
        for (int j = 0; j < 2; ++j) {
            b01[j][0] = *(const short8*)(bL + j * 1024 + o0);
            b01[j][1] = *(const short8*)(bL + j * 1024 + o1);
        }
        if (t + 1 < NT) SA(0, (t + 1) & 1, t + 1);
        __builtin_amdgcn_s_barrier();
        asm volatile("s_waitcnt lgkmcnt(0)" ::: "memory");
        __builtin_amdgcn_sched_barrier(0);
        __builtin_amdgcn_s_setprio(1);
        #pragma unroll
        for (int i = 0; i < 4; ++i)
            #pragma unroll
            for (int j = 0; j < 2; ++j) {
                acc[i][j] = MFMA16(am[i][0], b01[j][0], acc[i][j]);
                acc[i][j] = MFMA16(am[i][1], b01[j][1], acc[i][j]);
            }
        __builtin_amdgcn_s_setprio(0);
        __builtin_amdgcn_s_barrier();

        // ---------------- P2: read B23 (4 ds_read); stage (t+1)Ah1; Q(0,1)
        #pragma unroll
        for (int j = 0; j < 2; ++j) {
            b23[j][0] = *(const short8*)(bL + (2 + j) * 1024 + o0);
            b23[j][1] = *(const short8*)(bL + (2 + j) * 1024 + o1);
        }
        if (t + 1 < NT) SA(1, (t + 1) & 1, t + 1);
        __builtin_amdgcn_s_barrier();
        asm volatile("s_waitcnt lgkmcnt(0)" ::: "memory");
        __builtin_amdgcn_sched_barrier(0);
        __builtin_amdgcn_s_setprio(1);
        #pragma unroll
        for (int i = 0; i < 4; ++i)
            #pragma unroll
            for (int j = 0; j < 2; ++j) {
                acc[i][2 + j] = MFMA16(am[i][0], b23[j][0], acc[i][2 + j]);
                acc[i][2 + j] = MFMA16(am[i][1], b23[j][1], acc[i][2 + j]);
            }
        __builtin_amdgcn_s_setprio(0);
        __builtin_amdgcn_s_barrier();

        // ---------------- P3: read A1(m4-7, reuse regs, 8 ds_read); stage (t+2)Bh0; Q(1,1)
        #pragma unroll
        for (int i = 0; i < 4; ++i) {
            am[i][0] = *(const short8*)(aL + (4 + i) * 1024 + o0);
            am[i][1] = *(const short8*)(aL + (4 + i) * 1024 + o1);
        }
        if (t + 2 < NT) SB(0, b, t + 2);   // buf (t+2)&1 == b; tile-t B reads drained before P2 bar#2
        __builtin_amdgcn_s_barrier();
        asm volatile("s_waitcnt lgkmcnt(0)" ::: "memory");
        __builtin_amdgcn_sched_barrier(0);
        __builtin_amdgcn_s_setprio(1);
        #pragma unroll
        for (int i = 0; i < 4; ++i)
            #pragma unroll
            for (int j = 0; j < 2; ++j) {
                acc[4 + i][2 + j] = MFMA16(am[i][0], b23[j][0], acc[4 + i][2 + j]);
                acc[4 + i][2 + j] = MFMA16(am[i][1], b23[j][1], acc[4 + i][2 + j]);
            }
        __builtin_amdgcn_s_setprio(0);
        __builtin_amdgcn_s_barrier();

        // ---------------- P4: stage (t+2)Bh1; Q(1,0); counted vmcnt; barrier
        if (t + 2 < NT) SB(1, b, t + 2);
        __builtin_amdgcn_s_barrier();
        __builtin_amdgcn_s_setprio(1);
        #pragma unroll
        for (int i = 0; i < 4; ++i)
            #pragma unroll
            for (int j = 0; j < 2; ++j) {
                acc[4 + i][j] = MFMA16(am[i][0], b01[j][0], acc[4 + i][j]);
                acc[4 + i][j] = MFMA16(am[i][1], b01[j][1], acc[4 + i][j]);
            }
        __builtin_amdgcn_s_setprio(0);
        // ensure tile t+1 fully landed; keep (t+2) B halves (4 loads) in flight
        if (t + 2 < NT)       asm volatile("s_waitcnt vmcnt(4)" ::: "memory");
        else if (t + 2 == NT) asm volatile("s_waitcnt vmcnt(0)" ::: "memory");
        __builtin_amdgcn_s_barrier();
    }

    // ---- epilogue: C/D layout col = lane&15, row = (lane>>4)*4 + reg  [m89]
    const int row0 = bm * 256 + wr * 128 + q * 4;
    const int col0 = bn * 256 + wc * 64 + r;
    #pragma unroll
    for (int i = 0; i < 8; ++i)
        #pragma unroll
        for (int j = 0; j < 4; ++j)
            #pragma unroll
            for (int v = 0; v < 4; ++v)
                C[(size_t)(row0 + i * 16 + v) * N_DIM + col0 + j * 16] = alpha * acc[i][j][v];
}

// ---------------------------------------------------------------------------
extern "C" void kernel_launch(void* const* d_in, const int* in_sizes, int n_in,
                              void* d_out, int out_size, void* d_ws, size_t ws_size,
                              hipStream_t stream) {
    const float* x = (const float*)d_in[0];  // 4*2048*4096 fp32
    const float* w = (const float*)d_in[1];  // 4096*4096 fp32
    float* out = (float*)d_out;              // 8192*4096 fp32

    char* ws = (char*)d_ws;
    double* partial = (double*)ws;                          // 8 KB
    float* alpha = (float*)(ws + 8192);                     // 4 B
    ushort* qw = (ushort*)(ws + 16384);                     // 32 MB (N x K bf16 ternary)
    ushort* xb = (ushort*)(ws + 16384 + (size_t)K_DIM * N_DIM * 2);  // 64 MB (M x K bf16)

    k_abs_partial<<<1024, 256, 0, stream>>>(w, partial);
    k_alpha<<<1, 256, 0, stream>>>(partial, alpha);
    k_quant<<<(K_DIM * N_DIM / 4) / 256, 256, 0, stream>>>(w, alpha, qw);
    k_cast<<<(M_DIM * K_DIM / 4) / 256, 256, 0, stream>>>(x, xb);

    // 256x256 tiles: (8192/256)*(4096/256) = 32*16 = 512 blocks of 512 threads
    k_gemm<<<512, 512, 0, stream>>>(xb, qw, alpha, out);
}